// Round 2
// baseline (195.646 us; speedup 1.0000x reference)
//
#include <hip/hip_runtime.h>

#define NB 32
#define TMAX 512
#define DDIM 384
#define TOUT (TMAX * 7)   // 3584
#define D4 (DDIM / 4)     // 96 float4 per frame
#define FPB 16            // frames per block in expand kernel
#define EPT 6             // float4 per thread = FPB*D4/256

// Kernel 1: per-batch masked cumsum (with all-zero fallback), then scatter
// the frame->token index table directly:
//   idx[b][f] = t  for f in [cum[t-1], cum[t])   (ranges are disjoint)
//   idx[b][f] = 0  for f in [total, TOUT)        (masked later anyway)
// Also writes totals[b]. One block per batch, TMAX threads.
__global__ __launch_bounds__(TMAX) void lr_scan_scatter(
        const int* __restrict__ ds,
        const int* __restrict__ ilens,
        int* __restrict__ idx,
        int* __restrict__ totals) {
    __shared__ int s[TMAX];
    const int b = blockIdx.x;
    const int t = threadIdx.x;
    const int len = ilens[b];

    int d = (t < len) ? ds[b * TMAX + t] : 0;
    s[t] = d;
    __syncthreads();

    // Hillis-Steele inclusive scan over 512 elements.
    for (int off = 1; off < TMAX; off <<= 1) {
        int v = (t >= off) ? s[t - off] : 0;
        __syncthreads();
        s[t] += v;
        __syncthreads();
    }

    if (s[TMAX - 1] == 0) {   // uniform branch: masked durations all zero
        __syncthreads();
        s[t] = (t < len) ? 1 : 0;
        __syncthreads();
        for (int off = 1; off < TMAX; off <<= 1) {
            int v = (t >= off) ? s[t - off] : 0;
            __syncthreads();
            s[t] += v;
            __syncthreads();
        }
    }

    const int total = s[TMAX - 1];
    const int start = (t == 0) ? 0 : s[t - 1];
    const int end   = s[t];

    // Scatter this token's frame range (<= 7 iterations, disjoint across t).
    for (int f = start; f < end; ++f) idx[b * TOUT + f] = t;
    // Zero-fill the invalid tail so expand reads in-bounds.
    for (int f = total + t; f < TOUT; f += TMAX) idx[b * TOUT + f] = 0;
    if (t == 0) totals[b] = total;
}

// Kernel 2: pure streaming expand. Each block = FPB consecutive frames of one
// batch. Critical path: a 64 B idx load + one barrier, then EPT independent
// gather-load -> coalesced-store float4 pairs per thread.
__global__ __launch_bounds__(256) void lr_expand_kernel(
        const float4* __restrict__ xs,
        const int* __restrict__ idx,
        const int* __restrict__ totals,
        float4* __restrict__ out) {
    __shared__ int s_idx[FPB];

    const int b  = blockIdx.y;
    const int f0 = blockIdx.x * FPB;
    const int t  = threadIdx.x;

    if (t < FPB) s_idx[t] = idx[b * TOUT + f0 + t];
    const int total = totals[b];   // wave-uniform -> scalar load
    __syncthreads();

    const int base_out = (b * TOUT + f0) * D4;
    const int base_xs  = b * TMAX * D4;

    float4 v[EPT];
#pragma unroll
    for (int i = 0; i < EPT; ++i) {
        const int l   = i * 256 + t;     // 0..1535, contiguous across threads
        const int fl  = l / D4;          // local frame 0..15
        const int col = l - fl * D4;     // 0..95
        v[i] = make_float4(0.f, 0.f, 0.f, 0.f);
        if (f0 + fl < total) {
            v[i] = xs[base_xs + s_idx[fl] * D4 + col];
        }
    }
#pragma unroll
    for (int i = 0; i < EPT; ++i) {
        out[base_out + i * 256 + t] = v[i];
    }
}

extern "C" void kernel_launch(void* const* d_in, const int* in_sizes, int n_in,
                              void* d_out, int out_size, void* d_ws, size_t ws_size,
                              hipStream_t stream) {
    const float* xs    = (const float*)d_in[0];
    const int*   ds    = (const int*)d_in[1];
    const int*   ilens = (const int*)d_in[2];
    float*       out   = (float*)d_out;

    int* idx    = (int*)d_ws;                 // B*TOUT ints = 458752 B
    int* totals = idx + NB * TOUT;            // 32 ints

    lr_scan_scatter<<<NB, TMAX, 0, stream>>>(ds, ilens, idx, totals);

    dim3 grid(TOUT / FPB, NB);
    lr_expand_kernel<<<grid, 256, 0, stream>>>(
        (const float4*)xs, idx, totals, (float4*)out);
}